// Round 1
// baseline (713.835 us; speedup 1.0000x reference)
//
#include <hip/hip_runtime.h>
#include <hip/hip_bf16.h>
#include <math.h>

#define N_NODES 10000
#define N_EDGES 320000
#define IN_SIZE 256
#define H1 8
#define D1 64
#define F1 512
#define H2 1
#define D2 64
#define F2 64

// ---- ordered-uint encoding for float atomicMax (exact, order-independent) ----
__device__ __forceinline__ unsigned enc_f32(float x) {
  unsigned u = __float_as_uint(x);
  return (u & 0x80000000u) ? ~u : (u | 0x80000000u);
}
__device__ __forceinline__ float dec_f32(unsigned u) {
  unsigned v = (u & 0x80000000u) ? (u & 0x7fffffffu) : ~u;
  return __uint_as_float(v);
}

// ---- simple LDS-tiled f32 GEMM: C[M,Ncols] = A[M,K] @ B[K,Ncols] ----
__global__ __launch_bounds__(256) void gemm_f32(const float* __restrict__ A,
                                                const float* __restrict__ B,
                                                float* __restrict__ C,
                                                int M, int Ncols, int K) {
  __shared__ float As[64][17];
  __shared__ float Bs[16][64];
  int tid = threadIdx.x;
  int tx = tid & 15, ty = tid >> 4;
  int rowBase = blockIdx.y * 64;
  int colBase = blockIdx.x * 64;
  int ar = tid >> 2;            // 0..63 (A tile row)
  int ak = (tid & 3) << 2;      // 0,4,8,12 (A tile k)
  int br = tid >> 4;            // 0..15 (B tile k)
  int bc = (tid & 15) << 2;     // 0..60 (B tile col)
  float acc[4][4] = {{0.f, 0.f, 0.f, 0.f}};
  for (int k0 = 0; k0 < K; k0 += 16) {
    float4 av = make_float4(0.f, 0.f, 0.f, 0.f);
    if (rowBase + ar < M)
      av = *reinterpret_cast<const float4*>(&A[(size_t)(rowBase + ar) * K + k0 + ak]);
    float4 bv = *reinterpret_cast<const float4*>(&B[(size_t)(k0 + br) * Ncols + colBase + bc]);
    __syncthreads();
    As[ar][ak + 0] = av.x; As[ar][ak + 1] = av.y;
    As[ar][ak + 2] = av.z; As[ar][ak + 3] = av.w;
    *reinterpret_cast<float4*>(&Bs[br][bc]) = bv;
    __syncthreads();
#pragma unroll
    for (int k = 0; k < 16; ++k) {
      float a0 = As[ty * 4 + 0][k], a1 = As[ty * 4 + 1][k];
      float a2 = As[ty * 4 + 2][k], a3 = As[ty * 4 + 3][k];
      float b0 = Bs[k][tx * 4 + 0], b1 = Bs[k][tx * 4 + 1];
      float b2 = Bs[k][tx * 4 + 2], b3 = Bs[k][tx * 4 + 3];
      acc[0][0] += a0 * b0; acc[0][1] += a0 * b1; acc[0][2] += a0 * b2; acc[0][3] += a0 * b3;
      acc[1][0] += a1 * b0; acc[1][1] += a1 * b1; acc[1][2] += a1 * b2; acc[1][3] += a1 * b3;
      acc[2][0] += a2 * b0; acc[2][1] += a2 * b1; acc[2][2] += a2 * b2; acc[2][3] += a2 * b3;
      acc[3][0] += a3 * b0; acc[3][1] += a3 * b1; acc[3][2] += a3 * b2; acc[3][3] += a3 * b3;
    }
  }
#pragma unroll
  for (int i = 0; i < 4; ++i) {
    int row = rowBase + ty * 4 + i;
    if (row < M) {
      float4 v = make_float4(acc[i][0], acc[i][1], acc[i][2], acc[i][3]);
      *reinterpret_cast<float4*>(&C[(size_t)row * Ncols + colBase + tx * 4]) = v;
    }
  }
}

// ---- per-node attention projections el/er (block = H*64 threads, 1 node/block) ----
__global__ void el_er_kernel(const float* __restrict__ ft, const float* __restrict__ al,
                             const float* __restrict__ ar, float* __restrict__ el,
                             float* __restrict__ er, int H) {
  int n = blockIdx.x;
  int t = threadIdx.x;
  float v = ft[(size_t)n * H * 64 + t];
  float pl = v * al[t];
  float pr = v * ar[t];
#pragma unroll
  for (int off = 32; off > 0; off >>= 1) {
    pl += __shfl_down(pl, off);
    pr += __shfl_down(pr, off);
  }
  if ((t & 63) == 0) {
    int h = t >> 6;
    el[n * H + h] = pl;
    er[n * H + h] = pr;
  }
}

// ---- CSR build ----
__global__ void hist_kernel(const int* __restrict__ dst, int* __restrict__ counts, int E) {
  int e = blockIdx.x * blockDim.x + threadIdx.x;
  if (e < E) atomicAdd(&counts[dst[e]], 1);
}

__global__ __launch_bounds__(1024) void scan_kernel(const int* __restrict__ counts,
                                                    int* __restrict__ row_off,
                                                    int* __restrict__ cursor, int N) {
  __shared__ int part[1024];
  int tid = threadIdx.x;
  int T = blockDim.x;
  int chunk = (N + T - 1) / T;
  int beg = tid * chunk;
  int end = min(beg + chunk, N);
  int s = 0;
  for (int i = beg; i < end; ++i) s += counts[i];
  part[tid] = s;
  __syncthreads();
  for (int off = 1; off < T; off <<= 1) {
    int v = (tid >= off) ? part[tid - off] : 0;
    __syncthreads();
    part[tid] += v;
    __syncthreads();
  }
  int run = (tid > 0) ? part[tid - 1] : 0;
  for (int i = beg; i < end; ++i) {
    row_off[i] = run;
    cursor[i] = run;
    run += counts[i];
  }
  if (tid == T - 1) row_off[N] = run;
}

__global__ void scatter_kernel(const int* __restrict__ dst, int* __restrict__ cursor,
                               int* __restrict__ eid, int E) {
  int e = blockIdx.x * blockDim.x + threadIdx.x;
  if (e < E) {
    int p = atomicAdd(&cursor[dst[e]], 1);
    eid[p] = e;
  }
}

// ---- edge logits + segment max ----
__global__ void edge_logits_kernel(const int* __restrict__ src, const int* __restrict__ dst,
                                   const float* __restrict__ el, const float* __restrict__ er,
                                   float* __restrict__ ebuf, unsigned* __restrict__ menc,
                                   int E, int H) {
  int e = blockIdx.x * blockDim.x + threadIdx.x;
  if (e >= E) return;
  int s = src[e], d = dst[e];
  for (int h = 0; h < H; ++h) {
    float x = el[s * H + h] + er[d * H + h];
    x = (x >= 0.f) ? x : 0.2f * x;
    ebuf[(size_t)e * H + h] = x;
    atomicMax(&menc[d * H + h], enc_f32(x));
  }
}

// ---- exp + segment denominator ----
__global__ void edge_exp_kernel(const int* __restrict__ dst, float* __restrict__ ebuf,
                                const unsigned* __restrict__ menc, float* __restrict__ denom,
                                int E, int H) {
  int e = blockIdx.x * blockDim.x + threadIdx.x;
  if (e >= E) return;
  int d = dst[e];
  for (int h = 0; h < H; ++h) {
    float m = dec_f32(menc[d * H + h]);
    if ((__float_as_uint(m) & 0x7f800000u) == 0x7f800000u) m = 0.f;  // !isfinite -> 0
    float ex = __expf(ebuf[(size_t)e * H + h] - m);
    ebuf[(size_t)e * H + h] = ex;
    atomicAdd(&denom[d * H + h], ex);
  }
}

// ---- per-dst-node aggregation over CSR row; block = H*D threads ----
__global__ void aggregate_kernel(const int* __restrict__ row_off, const int* __restrict__ eid,
                                 const int* __restrict__ src, const float* __restrict__ ebuf,
                                 const float* __restrict__ denom, const float* __restrict__ ft,
                                 const float* __restrict__ bias, float* __restrict__ out,
                                 int H, int D, int do_elu) {
  int n = blockIdx.x;
  int t = threadIdx.x;
  int HD = blockDim.x;
  int h = t / D;
  int beg = row_off[n], end = row_off[n + 1];
  float dn = denom[n * H + h];
  float inv = (dn > 0.f) ? (1.f / dn) : 0.f;
  float acc = 0.f;
  for (int i = beg; i < end; ++i) {
    int e = eid[i];
    int s = src[e];
    float a = ebuf[(size_t)e * H + h] * inv;
    acc += ft[(size_t)s * HD + t] * a;
  }
  float o = acc + bias[t];
  if (do_elu) o = (o > 0.f) ? o : (__expf(o) - 1.f);
  out[(size_t)n * HD + t] = o;
}

extern "C" void kernel_launch(void* const* d_in, const int* in_sizes, int n_in,
                              void* d_out, int out_size, void* d_ws, size_t ws_size,
                              hipStream_t stream) {
  const float* x   = (const float*)d_in[0];
  const int*   src = (const int*)d_in[1];
  const int*   dst = (const int*)d_in[2];
  const float* W1  = (const float*)d_in[3];
  const float* al1 = (const float*)d_in[4];
  const float* ar1 = (const float*)d_in[5];
  const float* b1  = (const float*)d_in[6];
  const float* W2  = (const float*)d_in[7];
  const float* al2 = (const float*)d_in[8];
  const float* ar2 = (const float*)d_in[9];
  const float* b2  = (const float*)d_in[10];
  float* out = (float*)d_out;

  char* ws = (char*)d_ws;
  size_t off = 0;
  auto alloc = [&](size_t bytes) -> void* {
    void* p = ws + off;
    off += (bytes + 255) & ~(size_t)255;
    return p;
  };
  // zero-init region (contiguous, one memset)
  size_t zbeg = off;
  unsigned* m1     = (unsigned*)alloc((size_t)N_NODES * H1 * 4);
  float*    dn1    = (float*)alloc((size_t)N_NODES * H1 * 4);
  unsigned* m2     = (unsigned*)alloc((size_t)N_NODES * 4);
  float*    dn2    = (float*)alloc((size_t)N_NODES * 4);
  int*      counts = (int*)alloc((size_t)N_NODES * 4);
  size_t zend = off;
  float* ft1 = (float*)alloc((size_t)N_NODES * F1 * 4);
  float* h1  = (float*)alloc((size_t)N_NODES * F1 * 4);
  float* ft2 = (float*)alloc((size_t)N_NODES * F2 * 4);
  float* el1 = (float*)alloc((size_t)N_NODES * H1 * 4);
  float* er1 = (float*)alloc((size_t)N_NODES * H1 * 4);
  float* el2 = (float*)alloc((size_t)N_NODES * 4);
  float* er2 = (float*)alloc((size_t)N_NODES * 4);
  float* e1  = (float*)alloc((size_t)N_EDGES * H1 * 4);
  float* e2  = (float*)alloc((size_t)N_EDGES * 4);
  int* row_off = (int*)alloc((size_t)(N_NODES + 1) * 4);
  int* cursor  = (int*)alloc((size_t)N_NODES * 4);
  int* eid     = (int*)alloc((size_t)N_EDGES * 4);
  (void)ws_size; (void)in_sizes; (void)n_in; (void)out_size;

  hipMemsetAsync(ws + zbeg, 0, zend - zbeg, stream);

  dim3 b256(256);
  int egrid = (N_EDGES + 255) / 256;

  // CSR build (independent of GEMMs)
  hist_kernel<<<egrid, b256, 0, stream>>>(dst, counts, N_EDGES);
  scan_kernel<<<1, 1024, 0, stream>>>(counts, row_off, cursor, N_NODES);
  scatter_kernel<<<egrid, b256, 0, stream>>>(dst, cursor, eid, N_EDGES);

  // ---- layer 1 ----
  gemm_f32<<<dim3(F1 / 64, (N_NODES + 63) / 64), b256, 0, stream>>>(x, W1, ft1, N_NODES, F1, IN_SIZE);
  el_er_kernel<<<N_NODES, H1 * 64, 0, stream>>>(ft1, al1, ar1, el1, er1, H1);
  edge_logits_kernel<<<egrid, b256, 0, stream>>>(src, dst, el1, er1, e1, m1, N_EDGES, H1);
  edge_exp_kernel<<<egrid, b256, 0, stream>>>(dst, e1, m1, dn1, N_EDGES, H1);
  aggregate_kernel<<<N_NODES, F1, 0, stream>>>(row_off, eid, src, e1, dn1, ft1, b1, h1, H1, D1, 1);

  // ---- layer 2 ----
  gemm_f32<<<dim3(F2 / 64, (N_NODES + 63) / 64), b256, 0, stream>>>(h1, W2, ft2, N_NODES, F2, F1);
  el_er_kernel<<<N_NODES, 64, 0, stream>>>(ft2, al2, ar2, el2, er2, H2);
  edge_logits_kernel<<<egrid, b256, 0, stream>>>(src, dst, el2, er2, e2, m2, N_EDGES, H2);
  edge_exp_kernel<<<egrid, b256, 0, stream>>>(dst, e2, m2, dn2, N_EDGES, H2);
  aggregate_kernel<<<N_NODES, F2, 0, stream>>>(row_off, eid, src, e2, dn2, ft2, b2, out, H2, D2, 0);
}

// Round 2
// 573.555 us; speedup vs baseline: 1.2446x; 1.2446x over previous
//
#include <hip/hip_runtime.h>
#include <hip/hip_bf16.h>
#include <math.h>

#define N_NODES 10000
#define N_EDGES 320000
#define IN_SIZE 256
#define H1 8
#define D1 64
#define F1 512
#define H2 1
#define D2 64
#define F2 64

// ---- ordered-uint encoding for float atomicMax (exact, order-independent) ----
__device__ __forceinline__ unsigned enc_f32(float x) {
  unsigned u = __float_as_uint(x);
  return (u & 0x80000000u) ? ~u : (u | 0x80000000u);
}
__device__ __forceinline__ float dec_f32(unsigned u) {
  unsigned v = (u & 0x80000000u) ? (u & 0x7fffffffu) : ~u;
  return __uint_as_float(v);
}

// ---- simple LDS-tiled f32 GEMM: C[M,Ncols] = A[M,K] @ B[K,Ncols] ----
__global__ __launch_bounds__(256) void gemm_f32(const float* __restrict__ A,
                                                const float* __restrict__ B,
                                                float* __restrict__ C,
                                                int M, int Ncols, int K) {
  __shared__ float As[64][17];
  __shared__ float Bs[16][64];
  int tid = threadIdx.x;
  int tx = tid & 15, ty = tid >> 4;
  int rowBase = blockIdx.y * 64;
  int colBase = blockIdx.x * 64;
  int ar = tid >> 2;            // 0..63 (A tile row)
  int ak = (tid & 3) << 2;      // 0,4,8,12 (A tile k)
  int br = tid >> 4;            // 0..15 (B tile k)
  int bc = (tid & 15) << 2;     // 0..60 (B tile col)
  float acc[4][4] = {{0.f, 0.f, 0.f, 0.f}};
  for (int k0 = 0; k0 < K; k0 += 16) {
    float4 av = make_float4(0.f, 0.f, 0.f, 0.f);
    if (rowBase + ar < M)
      av = *reinterpret_cast<const float4*>(&A[(size_t)(rowBase + ar) * K + k0 + ak]);
    float4 bv = *reinterpret_cast<const float4*>(&B[(size_t)(k0 + br) * Ncols + colBase + bc]);
    __syncthreads();
    As[ar][ak + 0] = av.x; As[ar][ak + 1] = av.y;
    As[ar][ak + 2] = av.z; As[ar][ak + 3] = av.w;
    *reinterpret_cast<float4*>(&Bs[br][bc]) = bv;
    __syncthreads();
#pragma unroll
    for (int k = 0; k < 16; ++k) {
      float a0 = As[ty * 4 + 0][k], a1 = As[ty * 4 + 1][k];
      float a2 = As[ty * 4 + 2][k], a3 = As[ty * 4 + 3][k];
      float b0 = Bs[k][tx * 4 + 0], b1 = Bs[k][tx * 4 + 1];
      float b2 = Bs[k][tx * 4 + 2], b3 = Bs[k][tx * 4 + 3];
      acc[0][0] += a0 * b0; acc[0][1] += a0 * b1; acc[0][2] += a0 * b2; acc[0][3] += a0 * b3;
      acc[1][0] += a1 * b0; acc[1][1] += a1 * b1; acc[1][2] += a1 * b2; acc[1][3] += a1 * b3;
      acc[2][0] += a2 * b0; acc[2][1] += a2 * b1; acc[2][2] += a2 * b2; acc[2][3] += a2 * b3;
      acc[3][0] += a3 * b0; acc[3][1] += a3 * b1; acc[3][2] += a3 * b2; acc[3][3] += a3 * b3;
    }
  }
#pragma unroll
  for (int i = 0; i < 4; ++i) {
    int row = rowBase + ty * 4 + i;
    if (row < M) {
      float4 v = make_float4(acc[i][0], acc[i][1], acc[i][2], acc[i][3]);
      *reinterpret_cast<float4*>(&C[(size_t)row * Ncols + colBase + tx * 4]) = v;
    }
  }
}

// ---- per-node attention projections el/er (block = H*64 threads, 1 node/block) ----
__global__ void el_er_kernel(const float* __restrict__ ft, const float* __restrict__ al,
                             const float* __restrict__ ar, float* __restrict__ el,
                             float* __restrict__ er, int H) {
  int n = blockIdx.x;
  int t = threadIdx.x;
  float v = ft[(size_t)n * H * 64 + t];
  float pl = v * al[t];
  float pr = v * ar[t];
#pragma unroll
  for (int off = 32; off > 0; off >>= 1) {
    pl += __shfl_down(pl, off);
    pr += __shfl_down(pr, off);
  }
  if ((t & 63) == 0) {
    int h = t >> 6;
    el[n * H + h] = pl;
    er[n * H + h] = pr;
  }
}

// ---- CSR build ----
__global__ void hist_kernel(const int* __restrict__ dst, int* __restrict__ counts, int E) {
  int e = blockIdx.x * blockDim.x + threadIdx.x;
  if (e < E) atomicAdd(&counts[dst[e]], 1);
}

__global__ __launch_bounds__(1024) void scan_kernel(const int* __restrict__ counts,
                                                    int* __restrict__ row_off,
                                                    int* __restrict__ cursor, int N) {
  __shared__ int part[1024];
  int tid = threadIdx.x;
  int T = blockDim.x;
  int chunk = (N + T - 1) / T;
  int beg = tid * chunk;
  int end = min(beg + chunk, N);
  int s = 0;
  for (int i = beg; i < end; ++i) s += counts[i];
  part[tid] = s;
  __syncthreads();
  for (int off = 1; off < T; off <<= 1) {
    int v = (tid >= off) ? part[tid - off] : 0;
    __syncthreads();
    part[tid] += v;
    __syncthreads();
  }
  int run = (tid > 0) ? part[tid - 1] : 0;
  for (int i = beg; i < end; ++i) {
    row_off[i] = run;
    cursor[i] = run;
    run += counts[i];
  }
  if (tid == T - 1) row_off[N] = run;
}

// scatter: build CSR-ordered src list and remember each edge's CSR slot
__global__ void scatter_kernel(const int* __restrict__ src, const int* __restrict__ dst,
                               int* __restrict__ cursor, int* __restrict__ src_csr,
                               int* __restrict__ pos, int E) {
  int e = blockIdx.x * blockDim.x + threadIdx.x;
  if (e < E) {
    int p = atomicAdd(&cursor[dst[e]], 1);
    src_csr[p] = src[e];
    pos[e] = p;
  }
}

// ---- edge logits + segment max ----
__global__ void edge_logits_kernel(const int* __restrict__ src, const int* __restrict__ dst,
                                   const float* __restrict__ el, const float* __restrict__ er,
                                   float* __restrict__ ebuf, unsigned* __restrict__ menc,
                                   int E, int H) {
  int e = blockIdx.x * blockDim.x + threadIdx.x;
  if (e >= E) return;
  int s = src[e], d = dst[e];
  for (int h = 0; h < H; ++h) {
    float x = el[s * H + h] + er[d * H + h];
    x = (x >= 0.f) ? x : 0.2f * x;
    ebuf[(size_t)e * H + h] = x;
    atomicMax(&menc[d * H + h], enc_f32(x));
  }
}

// ---- exp + segment denominator; write exp into CSR slot ----
__global__ void edge_exp_kernel(const int* __restrict__ dst, const int* __restrict__ pos,
                                const float* __restrict__ ebuf,
                                const unsigned* __restrict__ menc,
                                float* __restrict__ ecsr, float* __restrict__ denom,
                                int E, int H) {
  int e = blockIdx.x * blockDim.x + threadIdx.x;
  if (e >= E) return;
  int d = dst[e];
  int p = pos[e];
  for (int h = 0; h < H; ++h) {
    float m = dec_f32(menc[d * H + h]);
    if ((__float_as_uint(m) & 0x7f800000u) == 0x7f800000u) m = 0.f;  // !isfinite -> 0
    float ex = __expf(ebuf[(size_t)e * H + h] - m);
    ecsr[(size_t)p * H + h] = ex;
    atomicAdd(&denom[d * H + h], ex);
  }
}

// ---- per-dst-node aggregation; 8-deep ILP, denom factored out of the loop ----
__global__ __launch_bounds__(512) void aggregate_kernel(
    const int* __restrict__ row_off, const int* __restrict__ src_csr,
    const float* __restrict__ ecsr, const float* __restrict__ denom,
    const float* __restrict__ ft, const float* __restrict__ bias,
    float* __restrict__ out, int H, int do_elu) {
  int n = blockIdx.x;
  int t = threadIdx.x;
  int HD = blockDim.x;
  int h = t >> 6;                 // D = 64 in both layers
  int beg = row_off[n], end = row_off[n + 1];
  float acc = 0.f;
  int i = beg;
  for (; i + 8 <= end; i += 8) {
    int s0 = src_csr[i + 0], s1 = src_csr[i + 1], s2 = src_csr[i + 2], s3 = src_csr[i + 3];
    int s4 = src_csr[i + 4], s5 = src_csr[i + 5], s6 = src_csr[i + 6], s7 = src_csr[i + 7];
    float a0 = ecsr[(size_t)(i + 0) * H + h], a1 = ecsr[(size_t)(i + 1) * H + h];
    float a2 = ecsr[(size_t)(i + 2) * H + h], a3 = ecsr[(size_t)(i + 3) * H + h];
    float a4 = ecsr[(size_t)(i + 4) * H + h], a5 = ecsr[(size_t)(i + 5) * H + h];
    float a6 = ecsr[(size_t)(i + 6) * H + h], a7 = ecsr[(size_t)(i + 7) * H + h];
    float f0 = ft[(size_t)s0 * HD + t], f1 = ft[(size_t)s1 * HD + t];
    float f2 = ft[(size_t)s2 * HD + t], f3 = ft[(size_t)s3 * HD + t];
    float f4 = ft[(size_t)s4 * HD + t], f5 = ft[(size_t)s5 * HD + t];
    float f6 = ft[(size_t)s6 * HD + t], f7 = ft[(size_t)s7 * HD + t];
    acc += f0 * a0; acc += f1 * a1; acc += f2 * a2; acc += f3 * a3;
    acc += f4 * a4; acc += f5 * a5; acc += f6 * a6; acc += f7 * a7;
  }
  for (; i < end; ++i) {
    int s = src_csr[i];
    float a = ecsr[(size_t)i * H + h];
    acc += ft[(size_t)s * HD + t] * a;
  }
  float dn = denom[n * H + h];
  float inv = (dn > 0.f) ? (1.f / dn) : 0.f;
  float o = acc * inv + bias[t];
  if (do_elu) o = (o > 0.f) ? o : (__expf(o) - 1.f);
  out[(size_t)n * HD + t] = o;
}

extern "C" void kernel_launch(void* const* d_in, const int* in_sizes, int n_in,
                              void* d_out, int out_size, void* d_ws, size_t ws_size,
                              hipStream_t stream) {
  const float* x   = (const float*)d_in[0];
  const int*   src = (const int*)d_in[1];
  const int*   dst = (const int*)d_in[2];
  const float* W1  = (const float*)d_in[3];
  const float* al1 = (const float*)d_in[4];
  const float* ar1 = (const float*)d_in[5];
  const float* b1  = (const float*)d_in[6];
  const float* W2  = (const float*)d_in[7];
  const float* al2 = (const float*)d_in[8];
  const float* ar2 = (const float*)d_in[9];
  const float* b2  = (const float*)d_in[10];
  float* out = (float*)d_out;

  char* ws = (char*)d_ws;
  size_t off = 0;
  auto alloc = [&](size_t bytes) -> void* {
    void* p = ws + off;
    off += (bytes + 255) & ~(size_t)255;
    return p;
  };
  // zero-init region (contiguous, one memset)
  size_t zbeg = off;
  unsigned* m1     = (unsigned*)alloc((size_t)N_NODES * H1 * 4);
  float*    dn1    = (float*)alloc((size_t)N_NODES * H1 * 4);
  unsigned* m2     = (unsigned*)alloc((size_t)N_NODES * 4);
  float*    dn2    = (float*)alloc((size_t)N_NODES * 4);
  int*      counts = (int*)alloc((size_t)N_NODES * 4);
  size_t zend = off;
  float* ft1 = (float*)alloc((size_t)N_NODES * F1 * 4);
  float* h1  = (float*)alloc((size_t)N_NODES * F1 * 4);
  float* ft2 = (float*)alloc((size_t)N_NODES * F2 * 4);
  float* el1 = (float*)alloc((size_t)N_NODES * H1 * 4);
  float* er1 = (float*)alloc((size_t)N_NODES * H1 * 4);
  float* el2 = (float*)alloc((size_t)N_NODES * 4);
  float* er2 = (float*)alloc((size_t)N_NODES * 4);
  float* e1  = (float*)alloc((size_t)N_EDGES * H1 * 4);
  float* e2  = (float*)alloc((size_t)N_EDGES * 4);
  float* ecsr = (float*)alloc((size_t)N_EDGES * H1 * 4);  // reused for layer 2 (H=1)
  int* row_off = (int*)alloc((size_t)(N_NODES + 1) * 4);
  int* cursor  = (int*)alloc((size_t)N_NODES * 4);
  int* src_csr = (int*)alloc((size_t)N_EDGES * 4);
  int* pos     = (int*)alloc((size_t)N_EDGES * 4);
  (void)ws_size; (void)in_sizes; (void)n_in; (void)out_size;

  hipMemsetAsync(ws + zbeg, 0, zend - zbeg, stream);

  dim3 b256(256);
  int egrid = (N_EDGES + 255) / 256;

  // CSR build (independent of GEMMs)
  hist_kernel<<<egrid, b256, 0, stream>>>(dst, counts, N_EDGES);
  scan_kernel<<<1, 1024, 0, stream>>>(counts, row_off, cursor, N_NODES);
  scatter_kernel<<<egrid, b256, 0, stream>>>(src, dst, cursor, src_csr, pos, N_EDGES);

  // ---- layer 1 ----
  gemm_f32<<<dim3(F1 / 64, (N_NODES + 63) / 64), b256, 0, stream>>>(x, W1, ft1, N_NODES, F1, IN_SIZE);
  el_er_kernel<<<N_NODES, H1 * 64, 0, stream>>>(ft1, al1, ar1, el1, er1, H1);
  edge_logits_kernel<<<egrid, b256, 0, stream>>>(src, dst, el1, er1, e1, m1, N_EDGES, H1);
  edge_exp_kernel<<<egrid, b256, 0, stream>>>(dst, pos, e1, m1, ecsr, dn1, N_EDGES, H1);
  aggregate_kernel<<<N_NODES, F1, 0, stream>>>(row_off, src_csr, ecsr, dn1, ft1, b1, h1, H1, 1);

  // ---- layer 2 ----
  gemm_f32<<<dim3(F2 / 64, (N_NODES + 63) / 64), b256, 0, stream>>>(h1, W2, ft2, N_NODES, F2, F1);
  el_er_kernel<<<N_NODES, 64, 0, stream>>>(ft2, al2, ar2, el2, er2, H2);
  edge_logits_kernel<<<egrid, b256, 0, stream>>>(src, dst, el2, er2, e2, m2, N_EDGES, H2);
  edge_exp_kernel<<<egrid, b256, 0, stream>>>(dst, pos, e2, m2, ecsr, dn2, N_EDGES, H2);
  aggregate_kernel<<<N_NODES, F2, 0, stream>>>(row_off, src_csr, ecsr, dn2, ft2, b2, out, H2, 0);
}

// Round 3
// 270.542 us; speedup vs baseline: 2.6385x; 2.1200x over previous
//
#include <hip/hip_runtime.h>
#include <hip/hip_bf16.h>
#include <math.h>

#define N_NODES 10000
#define N_EDGES 320000
#define IN_SIZE 256
#define H1 8
#define D1 64
#define F1 512
#define H2 1
#define D2 64
#define F2 64

// ---- simple LDS-tiled f32 GEMM: C[M,Ncols] = A[M,K] @ B[K,Ncols] ----
__global__ __launch_bounds__(256) void gemm_f32(const float* __restrict__ A,
                                                const float* __restrict__ B,
                                                float* __restrict__ C,
                                                int M, int Ncols, int K) {
  __shared__ float As[64][17];
  __shared__ float Bs[16][64];
  int tid = threadIdx.x;
  int tx = tid & 15, ty = tid >> 4;
  int rowBase = blockIdx.y * 64;
  int colBase = blockIdx.x * 64;
  int ar = tid >> 2;            // 0..63 (A tile row)
  int ak = (tid & 3) << 2;      // 0,4,8,12 (A tile k)
  int br = tid >> 4;            // 0..15 (B tile k)
  int bc = (tid & 15) << 2;     // 0..60 (B tile col)
  float acc[4][4] = {{0.f, 0.f, 0.f, 0.f}};
  for (int k0 = 0; k0 < K; k0 += 16) {
    float4 av = make_float4(0.f, 0.f, 0.f, 0.f);
    if (rowBase + ar < M)
      av = *reinterpret_cast<const float4*>(&A[(size_t)(rowBase + ar) * K + k0 + ak]);
    float4 bv = *reinterpret_cast<const float4*>(&B[(size_t)(k0 + br) * Ncols + colBase + bc]);
    __syncthreads();
    As[ar][ak + 0] = av.x; As[ar][ak + 1] = av.y;
    As[ar][ak + 2] = av.z; As[ar][ak + 3] = av.w;
    *reinterpret_cast<float4*>(&Bs[br][bc]) = bv;
    __syncthreads();
#pragma unroll
    for (int k = 0; k < 16; ++k) {
      float a0 = As[ty * 4 + 0][k], a1 = As[ty * 4 + 1][k];
      float a2 = As[ty * 4 + 2][k], a3 = As[ty * 4 + 3][k];
      float b0 = Bs[k][tx * 4 + 0], b1 = Bs[k][tx * 4 + 1];
      float b2 = Bs[k][tx * 4 + 2], b3 = Bs[k][tx * 4 + 3];
      acc[0][0] += a0 * b0; acc[0][1] += a0 * b1; acc[0][2] += a0 * b2; acc[0][3] += a0 * b3;
      acc[1][0] += a1 * b0; acc[1][1] += a1 * b1; acc[1][2] += a1 * b2; acc[1][3] += a1 * b3;
      acc[2][0] += a2 * b0; acc[2][1] += a2 * b1; acc[2][2] += a2 * b2; acc[2][3] += a2 * b3;
      acc[3][0] += a3 * b0; acc[3][1] += a3 * b1; acc[3][2] += a3 * b2; acc[3][3] += a3 * b3;
    }
  }
#pragma unroll
  for (int i = 0; i < 4; ++i) {
    int row = rowBase + ty * 4 + i;
    if (row < M) {
      float4 v = make_float4(acc[i][0], acc[i][1], acc[i][2], acc[i][3]);
      *reinterpret_cast<float4*>(&C[(size_t)row * Ncols + colBase + tx * 4]) = v;
    }
  }
}

// ---- per-node attention projections el/er (block = H*64 threads, 1 node/block) ----
__global__ void el_er_kernel(const float* __restrict__ ft, const float* __restrict__ al,
                             const float* __restrict__ ar, float* __restrict__ el,
                             float* __restrict__ er, int H) {
  int n = blockIdx.x;
  int t = threadIdx.x;
  float v = ft[(size_t)n * H * 64 + t];
  float pl = v * al[t];
  float pr = v * ar[t];
#pragma unroll
  for (int off = 32; off > 0; off >>= 1) {
    pl += __shfl_down(pl, off);
    pr += __shfl_down(pr, off);
  }
  if ((t & 63) == 0) {
    int h = t >> 6;
    el[n * H + h] = pl;
    er[n * H + h] = pr;
  }
}

// ---- CSR build ----
__global__ void hist_kernel(const int* __restrict__ dst, int* __restrict__ counts, int E) {
  int e = blockIdx.x * blockDim.x + threadIdx.x;
  if (e < E) atomicAdd(&counts[dst[e]], 1);
}

__global__ __launch_bounds__(1024) void scan_kernel(const int* __restrict__ counts,
                                                    int* __restrict__ row_off,
                                                    int* __restrict__ cursor, int N) {
  __shared__ int part[1024];
  int tid = threadIdx.x;
  int T = blockDim.x;
  int chunk = (N + T - 1) / T;
  int beg = tid * chunk;
  int end = min(beg + chunk, N);
  int s = 0;
  for (int i = beg; i < end; ++i) s += counts[i];
  part[tid] = s;
  __syncthreads();
  for (int off = 1; off < T; off <<= 1) {
    int v = (tid >= off) ? part[tid - off] : 0;
    __syncthreads();
    part[tid] += v;
    __syncthreads();
  }
  int run = (tid > 0) ? part[tid - 1] : 0;
  for (int i = beg; i < end; ++i) {
    row_off[i] = run;
    cursor[i] = run;
    run += counts[i];
  }
  if (tid == T - 1) row_off[N] = run;
}

// scatter: build CSR-ordered src list
__global__ void scatter_kernel(const int* __restrict__ src, const int* __restrict__ dst,
                               int* __restrict__ cursor, int* __restrict__ src_csr, int E) {
  int e = blockIdx.x * blockDim.x + threadIdx.x;
  if (e < E) {
    int p = atomicAdd(&cursor[dst[e]], 1);
    src_csr[p] = src[e];
  }
}

// ---- fused per-node GAT: logits -> online softmax -> weighted aggregation ----
// Wave w of the block owns (node, head); lane i covers edge i of each 64-edge
// chunk. No LDS, no block barriers, no global atomics: max/sum are wave
// shuffle reductions, (src, ex) broadcast to all lanes via __shfl.
template <int H, int NPB, int DO_ELU>
__global__ __launch_bounds__(NPB * H * 64) void gat_node_kernel(
    const int* __restrict__ row_off, const int* __restrict__ src_csr,
    const float* __restrict__ el, const float* __restrict__ er,
    const float* __restrict__ ft, const float* __restrict__ bias,
    float* __restrict__ out, int N) {
  constexpr int F = H * 64;
  int t = threadIdx.x;
  int w = t >> 6;
  int lane = t & 63;
  int n = blockIdx.x * NPB + w / H;
  int h = w % H;
  if (n >= N) return;
  int beg = row_off[n], end = row_off[n + 1];
  float er_h = er[n * H + h];
  float m_run = -INFINITY;
  float s_run = 0.f, acc = 0.f;
  const float* ftp = ft + h * 64 + lane;
  for (int c = beg; c < end; c += 64) {
    int cnt = end - c;
    if (cnt > 64) cnt = 64;
    int s_reg = 0;
    float lg = -INFINITY;
    if (lane < cnt) {
      s_reg = src_csr[c + lane];
      float xv = el[s_reg * H + h] + er_h;
      lg = (xv >= 0.f) ? xv : 0.2f * xv;
    }
    // wave max of logits
    float m_c = lg;
#pragma unroll
    for (int o = 32; o > 0; o >>= 1) m_c = fmaxf(m_c, __shfl_xor(m_c, o));
    float m_new = fmaxf(m_run, m_c);
    float ex = (lane < cnt) ? __expf(lg - m_new) : 0.f;
    // wave sum of exps
    float sum_c = ex;
#pragma unroll
    for (int o = 32; o > 0; o >>= 1) sum_c += __shfl_xor(sum_c, o);
    float scale = (m_run == -INFINITY) ? 0.f : __expf(m_run - m_new);
    acc *= scale;
    s_run = s_run * scale + sum_c;
    m_run = m_new;
    int i = 0;
    for (; i + 8 <= cnt; i += 8) {
      int si0 = __shfl(s_reg, i + 0), si1 = __shfl(s_reg, i + 1);
      int si2 = __shfl(s_reg, i + 2), si3 = __shfl(s_reg, i + 3);
      int si4 = __shfl(s_reg, i + 4), si5 = __shfl(s_reg, i + 5);
      int si6 = __shfl(s_reg, i + 6), si7 = __shfl(s_reg, i + 7);
      float e0 = __shfl(ex, i + 0), e1 = __shfl(ex, i + 1);
      float e2 = __shfl(ex, i + 2), e3 = __shfl(ex, i + 3);
      float e4 = __shfl(ex, i + 4), e5 = __shfl(ex, i + 5);
      float e6 = __shfl(ex, i + 6), e7 = __shfl(ex, i + 7);
      float f0 = ftp[(size_t)si0 * F], f1 = ftp[(size_t)si1 * F];
      float f2 = ftp[(size_t)si2 * F], f3 = ftp[(size_t)si3 * F];
      float f4 = ftp[(size_t)si4 * F], f5 = ftp[(size_t)si5 * F];
      float f6 = ftp[(size_t)si6 * F], f7 = ftp[(size_t)si7 * F];
      acc += e0 * f0; acc += e1 * f1; acc += e2 * f2; acc += e3 * f3;
      acc += e4 * f4; acc += e5 * f5; acc += e6 * f6; acc += e7 * f7;
    }
    for (; i < cnt; ++i) {
      int si = __shfl(s_reg, i);
      float ei = __shfl(ex, i);
      acc += ei * ftp[(size_t)si * F];
    }
  }
  float inv = (s_run > 0.f) ? (1.f / s_run) : 0.f;
  float o = acc * inv + bias[h * 64 + lane];
  if (DO_ELU) o = (o > 0.f) ? o : (__expf(o) - 1.f);
  out[(size_t)n * F + h * 64 + lane] = o;
}

extern "C" void kernel_launch(void* const* d_in, const int* in_sizes, int n_in,
                              void* d_out, int out_size, void* d_ws, size_t ws_size,
                              hipStream_t stream) {
  const float* x   = (const float*)d_in[0];
  const int*   src = (const int*)d_in[1];
  const int*   dst = (const int*)d_in[2];
  const float* W1  = (const float*)d_in[3];
  const float* al1 = (const float*)d_in[4];
  const float* ar1 = (const float*)d_in[5];
  const float* b1  = (const float*)d_in[6];
  const float* W2  = (const float*)d_in[7];
  const float* al2 = (const float*)d_in[8];
  const float* ar2 = (const float*)d_in[9];
  const float* b2  = (const float*)d_in[10];
  float* out = (float*)d_out;

  char* ws = (char*)d_ws;
  size_t off = 0;
  auto alloc = [&](size_t bytes) -> void* {
    void* p = ws + off;
    off += (bytes + 255) & ~(size_t)255;
    return p;
  };
  size_t zbeg = off;
  int* counts = (int*)alloc((size_t)N_NODES * 4);
  size_t zend = off;
  float* ft1 = (float*)alloc((size_t)N_NODES * F1 * 4);
  float* h1  = (float*)alloc((size_t)N_NODES * F1 * 4);
  float* ft2 = (float*)alloc((size_t)N_NODES * F2 * 4);
  float* el1 = (float*)alloc((size_t)N_NODES * H1 * 4);
  float* er1 = (float*)alloc((size_t)N_NODES * H1 * 4);
  float* el2 = (float*)alloc((size_t)N_NODES * 4);
  float* er2 = (float*)alloc((size_t)N_NODES * 4);
  int* row_off = (int*)alloc((size_t)(N_NODES + 1) * 4);
  int* cursor  = (int*)alloc((size_t)N_NODES * 4);
  int* src_csr = (int*)alloc((size_t)N_EDGES * 4);
  (void)ws_size; (void)in_sizes; (void)n_in; (void)out_size;

  hipMemsetAsync(ws + zbeg, 0, zend - zbeg, stream);

  dim3 b256(256);
  int egrid = (N_EDGES + 255) / 256;

  // CSR build
  hist_kernel<<<egrid, b256, 0, stream>>>(dst, counts, N_EDGES);
  scan_kernel<<<1, 1024, 0, stream>>>(counts, row_off, cursor, N_NODES);
  scatter_kernel<<<egrid, b256, 0, stream>>>(src, dst, cursor, src_csr, N_EDGES);

  // ---- layer 1 ----
  gemm_f32<<<dim3(F1 / 64, (N_NODES + 63) / 64), b256, 0, stream>>>(x, W1, ft1, N_NODES, F1, IN_SIZE);
  el_er_kernel<<<N_NODES, H1 * 64, 0, stream>>>(ft1, al1, ar1, el1, er1, H1);
  gat_node_kernel<H1, 1, 1><<<N_NODES, H1 * 64, 0, stream>>>(
      row_off, src_csr, el1, er1, ft1, b1, h1, N_NODES);

  // ---- layer 2 ----
  gemm_f32<<<dim3(F2 / 64, (N_NODES + 63) / 64), b256, 0, stream>>>(h1, W2, ft2, N_NODES, F2, F1);
  el_er_kernel<<<N_NODES, 64, 0, stream>>>(ft2, al2, ar2, el2, er2, H2);
  gat_node_kernel<H2, 4, 0><<<(N_NODES + 3) / 4, 4 * H2 * 64, 0, stream>>>(
      row_off, src_csr, el2, er2, ft2, b2, out, N_NODES);
}